// Round 5
// baseline (1051.887 us; speedup 1.0000x reference)
//
#include <hip/hip_runtime.h>
#include <stdint.h>
#include <stddef.h>

// ScaledDotProductAttention: B=64, Lq=Lk=2048, D=64, fp32 in/out.
// out tuple = (output [64][2048][64], attn [64][2048][2048]) concat in d_out.
// R5: SWAPPED QK^T (mfma(K,Q) -> S^T layout): lane owns q=l15, k=g*4..+3
// contiguous => mask loads f32x4, attn stores f32x4, no LDS transpose bounce.
// PV via mfma_f32_16x16x16f16 where the lane's exp values ARE the B-fragment.
// All operands fp16 (better mantissa than bf16). LDS only 18KB (O-reduce).

typedef __attribute__((ext_vector_type(4))) float f32x4;
typedef __fp16 f16x2 __attribute__((ext_vector_type(2)));
typedef __fp16 f16x4 __attribute__((ext_vector_type(4)));
typedef __fp16 f16x8 __attribute__((ext_vector_type(8)));

static constexpr int BATCH = 64;
static constexpr int SEQ   = 2048;   // lq == lk
static constexpr int HD    = 64;     // head dim
static constexpr float NEGH = -60000.0f;  // "-inf" that survives fp16

// ---------------- pre-pass: fp32 -> fp16 flat convert ----------------
__global__ void cvt_f16_kernel(const float* __restrict__ in,
                               __fp16* __restrict__ out, int n4) {
  int i = blockIdx.x * blockDim.x + threadIdx.x;
  if (i >= n4) return;
  f32x4 v = *(const f32x4*)(in + (size_t)i * 4);
  f16x4 o;
  o[0] = (__fp16)v[0]; o[1] = (__fp16)v[1];
  o[2] = (__fp16)v[2]; o[3] = (__fp16)v[3];
  *(f16x4*)(out + (size_t)i * 4) = o;
}

// ---------------- pre-pass: V [b][k][d] fp32 -> VT fp16 [b][d][k] ----------
__global__ void vtrans_kernel(const float* __restrict__ v,
                              __fp16* __restrict__ vt) {
  __shared__ float tile[64][65];
  const int b  = blockIdx.x >> 5;
  const int k0 = (blockIdx.x & 31) << 6;
  const int t  = threadIdx.x;
  const int kk = t >> 4;
  const int d4 = (t & 15) << 2;
#pragma unroll
  for (int i = 0; i < 4; ++i) {
    f32x4 val = *(const f32x4*)(v + ((size_t)(b * SEQ + k0 + kk + 16 * i)) * HD + d4);
    tile[kk + 16 * i][d4 + 0] = val[0];
    tile[kk + 16 * i][d4 + 1] = val[1];
    tile[kk + 16 * i][d4 + 2] = val[2];
    tile[kk + 16 * i][d4 + 3] = val[3];
  }
  __syncthreads();
  const int d  = t >> 2;
  const int ks = (t & 3) << 4;
  f16x8 o0, o1;
#pragma unroll
  for (int j = 0; j < 8; ++j) o0[j] = (__fp16)tile[ks + j][d];
#pragma unroll
  for (int j = 0; j < 8; ++j) o1[j] = (__fp16)tile[ks + 8 + j][d];
  __fp16* dst = vt + ((size_t)(b * HD + d)) * SEQ + k0 + ks;
  *(f16x8*)(dst)     = o0;
  *(f16x8*)(dst + 8) = o1;
}

// ---------------- main fused attention ----------------
// grid: 64 batches x 128 q-tiles; block 256 (4 waves); wave w owns k-range
// [w*512, w*512+512). Lane (g,l15): q-row = l15, k = tile*16 + g*4 + {0..3}.
__global__ __launch_bounds__(256, 2) void attn_kernel(
    const __fp16* __restrict__ qh,
    const __fp16* __restrict__ kh,
    const __fp16* __restrict__ vth,
    const float* __restrict__ mask,
    float* __restrict__ out,
    float* __restrict__ attn) {
  __shared__ float s_red[4 * 64 * 17];   // [wave][d][q(+pad)] O partials
  __shared__ float stat_m[4][16];
  __shared__ float stat_l[4][16];

  const int tid  = threadIdx.x;
  const int w    = tid >> 6;
  const int lane = tid & 63;
  const int l15  = lane & 15;
  const int g    = lane >> 4;   // 16-lane group 0..3
  const int g4   = g << 2;
  const int g8   = g << 3;

  const int b   = blockIdx.x >> 7;
  const int q0  = (blockIdx.x & 127) << 4;
  const int wk0 = w << 9;

  // Q = B operand (col=l15 -> q-row, k=g*8+j -> head-dim)
  const __fp16* qptr = qh + ((size_t)(b * SEQ + q0 + l15)) * HD;
  const f16x8 qb0 = *(const f16x8*)(qptr + g8);
  const f16x8 qb1 = *(const f16x8*)(qptr + 32 + g8);

  // K = A operand (row=l15 -> k-row within tile, k=g*8+j -> head-dim)
  const __fp16* kbase = kh + ((size_t)(b * SEQ + wk0 + l15)) * HD;
  const float*  mptr  = mask + ((size_t)(b * SEQ) + q0 + l15) * (size_t)SEQ + wk0 + g4;

  // ---- Phase A: S^T = (QK^T)^T/8 + mask -> packed fp16 regs + running max --
  f16x2 ph[64];     // 32 tiles x 4 k-values (pairs)
  f32x4 mbuf[4];    // 4-deep mask prefetch (vector!)
  f16x8 kbuf[2][2]; // 2-deep K prefetch
  float m = -3.0e38f;

  kbuf[0][0] = *(const f16x8*)(kbase + g8);
  kbuf[0][1] = *(const f16x8*)(kbase + 32 + g8);
  kbuf[1][0] = *(const f16x8*)(kbase + 16 * HD + g8);
  kbuf[1][1] = *(const f16x8*)(kbase + 16 * HD + 32 + g8);
#pragma unroll
  for (int i = 0; i < 4; ++i)
    mbuf[i] = __builtin_nontemporal_load((const f32x4*)(mptr + i * 16));

#pragma unroll
  for (int t = 0; t < 32; ++t) {
    f32x4 acc = {0.f, 0.f, 0.f, 0.f};
    acc = __builtin_amdgcn_mfma_f32_16x16x32_f16(kbuf[t & 1][0], qb0, acc, 0, 0, 0);
    acc = __builtin_amdgcn_mfma_f32_16x16x32_f16(kbuf[t & 1][1], qb1, acc, 0, 0, 0);
    if (t + 2 < 32) {
      const __fp16* kp = kbase + (size_t)(t + 2) * (16 * HD);
      kbuf[t & 1][0] = *(const f16x8*)(kp + g8);
      kbuf[t & 1][1] = *(const f16x8*)(kp + 32 + g8);
    }
    const f32x4 mv = mbuf[t & 3];
    if (t + 4 < 32)
      mbuf[t & 3] = __builtin_nontemporal_load((const f32x4*)(mptr + (t + 4) * 16));
    float s0 = (mv[0] < 0.f) ? NEGH : fmaf(acc[0], 0.125f, mv[0]);
    float s1 = (mv[1] < 0.f) ? NEGH : fmaf(acc[1], 0.125f, mv[1]);
    float s2 = (mv[2] < 0.f) ? NEGH : fmaf(acc[2], 0.125f, mv[2]);
    float s3 = (mv[3] < 0.f) ? NEGH : fmaf(acc[3], 0.125f, mv[3]);
    m = fmaxf(m, fmaxf(fmaxf(s0, s1), fmaxf(s2, s3)));
    ph[2 * t]     = __builtin_amdgcn_cvt_pkrtz(s0, s1);
    ph[2 * t + 1] = __builtin_amdgcn_cvt_pkrtz(s2, s3);
  }
  // row max across the 4 g-groups holding the same q-row
  m = fmaxf(m, __shfl_xor(m, 16));
  m = fmaxf(m, __shfl_xor(m, 32));

  // ---- Phase A2: e = exp(s - m), sum, repack e over s ----
  float lw = 0.f;
#pragma unroll
  for (int t = 0; t < 32; ++t) {
    f16x2 h0 = ph[2 * t], h1 = ph[2 * t + 1];
    float e0 = __expf((float)h0[0] - m);
    float e1 = __expf((float)h0[1] - m);
    float e2 = __expf((float)h1[0] - m);
    float e3 = __expf((float)h1[1] - m);
    lw += (e0 + e1) + (e2 + e3);
    ph[2 * t]     = __builtin_amdgcn_cvt_pkrtz(e0, e1);
    ph[2 * t + 1] = __builtin_amdgcn_cvt_pkrtz(e2, e3);
  }
  lw += __shfl_xor(lw, 16);
  lw += __shfl_xor(lw, 32);

  if (lane < 16) { stat_m[w][lane] = m; stat_l[w][lane] = lw; }
  __syncthreads();

  float mg = -3.0e38f;
#pragma unroll
  for (int ww = 0; ww < 4; ++ww) mg = fmaxf(mg, stat_m[ww][l15]);
  float lg = 0.f;
#pragma unroll
  for (int ww = 0; ww < 4; ++ww) lg += stat_l[ww][l15] * __expf(stat_m[ww][l15] - mg);
  const float scale = __expf(m - mg) / lg;
  const __fp16 hs = (__fp16)scale;
  const f16x2 sc2 = {hs, hs};

  // ---- Phase B: attn stores (f32x4) + PV via 16x16x16 f16 MFMA ----
  f32x4 oacc[4];
#pragma unroll
  for (int db = 0; db < 4; ++db) oacc[db] = (f32x4){0.f, 0.f, 0.f, 0.f};

  float* attn_base = attn + ((size_t)(b * SEQ) + q0 + l15) * (size_t)SEQ + wk0 + g4;
  const __fp16* vbase = vth + ((size_t)(b * HD + l15)) * SEQ + wk0 + g4;

#pragma unroll
  for (int t = 0; t < 32; ++t) {
    // V^T A-fragments: row=l15 -> d (per 16-d block), k=g*4+j
    f16x4 vf0 = *(const f16x4*)(vbase + 0 * (16 * SEQ) + t * 16);
    f16x4 vf1 = *(const f16x4*)(vbase + 1 * (16 * SEQ) + t * 16);
    f16x4 vf2 = *(const f16x4*)(vbase + 2 * (16 * SEQ) + t * 16);
    f16x4 vf3 = *(const f16x4*)(vbase + 3 * (16 * SEQ) + t * 16);
    f16x2 e01 = ph[2 * t] * sc2;
    f16x2 e23 = ph[2 * t + 1] * sc2;
    f32x4 st;
    st[0] = (float)e01[0]; st[1] = (float)e01[1];
    st[2] = (float)e23[0]; st[3] = (float)e23[1];
    *(f32x4*)(attn_base + t * 16) = st;
    f16x4 pf;  // B-fragment: col=l15 -> q, k=g*4+j -> the lane's own 4 e's
    pf[0] = e01[0]; pf[1] = e01[1]; pf[2] = e23[0]; pf[3] = e23[1];
    oacc[0] = __builtin_amdgcn_mfma_f32_16x16x16f16(vf0, pf, oacc[0], 0, 0, 0);
    oacc[1] = __builtin_amdgcn_mfma_f32_16x16x16f16(vf1, pf, oacc[1], 0, 0, 0);
    oacc[2] = __builtin_amdgcn_mfma_f32_16x16x16f16(vf2, pf, oacc[2], 0, 0, 0);
    oacc[3] = __builtin_amdgcn_mfma_f32_16x16x16f16(vf3, pf, oacc[3], 0, 0, 0);
  }

  // ---- cross-wave partial-O reduction ----
  // oacc[db][r] = O^T[d = db*16 + g*4 + r][q = l15] (partial over wave's k)
#pragma unroll
  for (int db = 0; db < 4; ++db)
#pragma unroll
    for (int r = 0; r < 4; ++r)
      s_red[(size_t)w * 1088 + (db * 16 + g4 + r) * 17 + l15] = oacc[db][r];
  __syncthreads();

#pragma unroll
  for (int ii = 0; ii < 4; ++ii) {
    const int i = tid + ii * 256;     // i in [0,1024): q = i>>6, d = i&63
    const int q = i >> 6;
    const int d = i & 63;
    const int o = d * 17 + q;
    float s = s_red[o] + s_red[1088 + o] + s_red[2 * 1088 + o] + s_red[3 * 1088 + o];
    out[((size_t)(b * SEQ + q0 + q)) * HD + d] = s;
  }
}

extern "C" void kernel_launch(void* const* d_in, const int* in_sizes, int n_in,
                              void* d_out, int out_size, void* d_ws, size_t ws_size,
                              hipStream_t stream) {
  const float* q    = (const float*)d_in[0];
  const float* k    = (const float*)d_in[1];
  const float* v    = (const float*)d_in[2];
  const float* mask = (const float*)d_in[3];

  float* out  = (float*)d_out;
  float* attn = out + (size_t)BATCH * SEQ * HD;  // tuple: (output, attn)

  const size_t nqk = (size_t)BATCH * SEQ * HD;
  __fp16* qh = (__fp16*)d_ws;
  __fp16* kh = qh + nqk;
  __fp16* vt = kh + nqk;

  const int n4 = (int)(nqk / 4);
  cvt_f16_kernel<<<dim3((n4 + 255) / 256), dim3(256), 0, stream>>>(q, qh, n4);
  cvt_f16_kernel<<<dim3((n4 + 255) / 256), dim3(256), 0, stream>>>(k, kh, n4);
  vtrans_kernel<<<dim3(BATCH * (SEQ / 64)), dim3(256), 0, stream>>>(v, vt);
  attn_kernel<<<dim3(BATCH * (SEQ / 16)), dim3(256), 0, stream>>>(qh, kh, vt, mask, out, attn);
}

// Round 6
// 1047.348 us; speedup vs baseline: 1.0043x; 1.0043x over previous
//
#include <hip/hip_runtime.h>
#include <stdint.h>
#include <stddef.h>

// ScaledDotProductAttention: B=64, Lq=Lk=2048, D=64, fp32 in/out.
// out tuple = (output [64][2048][64], attn [64][2048][2048]) concat in d_out.
// R6: R5 structure (swapped MFMA -> lane owns q=l15, k=g*4..+3 contiguous;
// f32x4 mask loads / attn stores; no LDS transpose) + DEEP EQUALIZED
// pipelines: mask 8-deep, K 4-deep, V 4-deep, all refilled at a fixed issue
// point per unrolled iteration so vmcnt waits don't drain the mask pipe.

typedef __attribute__((ext_vector_type(4))) float f32x4;
typedef __fp16 f16x2 __attribute__((ext_vector_type(2)));
typedef __fp16 f16x4 __attribute__((ext_vector_type(4)));
typedef __fp16 f16x8 __attribute__((ext_vector_type(8)));

static constexpr int BATCH = 64;
static constexpr int SEQ   = 2048;   // lq == lk
static constexpr int HD    = 64;     // head dim
static constexpr float NEGH = -60000.0f;  // "-inf" that survives fp16

// ---------------- pre-pass: fp32 -> fp16 flat convert ----------------
__global__ void cvt_f16_kernel(const float* __restrict__ in,
                               __fp16* __restrict__ out, int n4) {
  int i = blockIdx.x * blockDim.x + threadIdx.x;
  if (i >= n4) return;
  f32x4 v = *(const f32x4*)(in + (size_t)i * 4);
  f16x4 o;
  o[0] = (__fp16)v[0]; o[1] = (__fp16)v[1];
  o[2] = (__fp16)v[2]; o[3] = (__fp16)v[3];
  *(f16x4*)(out + (size_t)i * 4) = o;
}

// ---------------- pre-pass: V [b][k][d] fp32 -> VT fp16 [b][d][k] ----------
__global__ void vtrans_kernel(const float* __restrict__ v,
                              __fp16* __restrict__ vt) {
  __shared__ float tile[64][65];
  const int b  = blockIdx.x >> 5;
  const int k0 = (blockIdx.x & 31) << 6;
  const int t  = threadIdx.x;
  const int kk = t >> 4;
  const int d4 = (t & 15) << 2;
#pragma unroll
  for (int i = 0; i < 4; ++i) {
    f32x4 val = *(const f32x4*)(v + ((size_t)(b * SEQ + k0 + kk + 16 * i)) * HD + d4);
    tile[kk + 16 * i][d4 + 0] = val[0];
    tile[kk + 16 * i][d4 + 1] = val[1];
    tile[kk + 16 * i][d4 + 2] = val[2];
    tile[kk + 16 * i][d4 + 3] = val[3];
  }
  __syncthreads();
  const int d  = t >> 2;
  const int ks = (t & 3) << 4;
  f16x8 o0, o1;
#pragma unroll
  for (int j = 0; j < 8; ++j) o0[j] = (__fp16)tile[ks + j][d];
#pragma unroll
  for (int j = 0; j < 8; ++j) o1[j] = (__fp16)tile[ks + 8 + j][d];
  __fp16* dst = vt + ((size_t)(b * HD + d)) * SEQ + k0 + ks;
  *(f16x8*)(dst)     = o0;
  *(f16x8*)(dst + 8) = o1;
}

// ---------------- main fused attention ----------------
// grid: 64 batches x 128 q-tiles; block 256 (4 waves); wave w owns k-range
// [w*512, w*512+512). Lane (g,l15): q-row = l15, k = tile*16 + g*4 + {0..3}.
__global__ __launch_bounds__(256, 2) void attn_kernel(
    const __fp16* __restrict__ qh,
    const __fp16* __restrict__ kh,
    const __fp16* __restrict__ vth,
    const float* __restrict__ mask,
    float* __restrict__ out,
    float* __restrict__ attn) {
  __shared__ float s_red[4 * 64 * 17];   // [wave][d][q(+pad)] O partials
  __shared__ float stat_m[4][16];
  __shared__ float stat_l[4][16];

  const int tid  = threadIdx.x;
  const int w    = tid >> 6;
  const int lane = tid & 63;
  const int l15  = lane & 15;
  const int g    = lane >> 4;   // 16-lane group 0..3
  const int g4   = g << 2;
  const int g8   = g << 3;

  const int b   = blockIdx.x >> 7;
  const int q0  = (blockIdx.x & 127) << 4;
  const int wk0 = w << 9;

  // Q = B operand (col=l15 -> q-row, k=g*8+j -> head-dim)
  const __fp16* qptr = qh + ((size_t)(b * SEQ + q0 + l15)) * HD;
  const f16x8 qb0 = *(const f16x8*)(qptr + g8);
  const f16x8 qb1 = *(const f16x8*)(qptr + 32 + g8);

  // K = A operand (row=l15 -> k-row within tile, k=g*8+j -> head-dim)
  const __fp16* kbase = kh + ((size_t)(b * SEQ + wk0 + l15)) * HD;
  const float*  mptr  = mask + ((size_t)(b * SEQ) + q0 + l15) * (size_t)SEQ + wk0 + g4;

  // ---- Phase A: S^T = (QK^T)^T/8 + mask -> packed fp16 regs + running max --
  f16x2 ph[64];      // 32 tiles x 4 k-values (pairs)
  f32x4 mbuf[8];     // 8-deep mask pipeline (HBM, ~900cy)
  f16x8 kbuf[4][2];  // 4-deep K pipeline (L2-resident)
  float m = -3.0e38f;

#pragma unroll
  for (int i = 0; i < 8; ++i)
    mbuf[i] = __builtin_nontemporal_load((const f32x4*)(mptr + i * 16));
#pragma unroll
  for (int i = 0; i < 4; ++i) {
    const __fp16* kp = kbase + (size_t)i * (16 * HD);
    kbuf[i][0] = *(const f16x8*)(kp + g8);
    kbuf[i][1] = *(const f16x8*)(kp + 32 + g8);
  }

#pragma unroll
  for (int t = 0; t < 32; ++t) {
    f32x4 acc = {0.f, 0.f, 0.f, 0.f};
    acc = __builtin_amdgcn_mfma_f32_16x16x32_f16(kbuf[t & 3][0], qb0, acc, 0, 0, 0);
    acc = __builtin_amdgcn_mfma_f32_16x16x32_f16(kbuf[t & 3][1], qb1, acc, 0, 0, 0);
    const f32x4 mv = mbuf[t & 7];
    // fixed issue point: refill K then mask, same lookahead ordering each iter
    if (t + 4 < 32) {
      const __fp16* kp = kbase + (size_t)(t + 4) * (16 * HD);
      kbuf[t & 3][0] = *(const f16x8*)(kp + g8);
      kbuf[t & 3][1] = *(const f16x8*)(kp + 32 + g8);
    }
    if (t + 8 < 32)
      mbuf[t & 7] = __builtin_nontemporal_load((const f32x4*)(mptr + (t + 8) * 16));
    float s0 = (mv[0] < 0.f) ? NEGH : fmaf(acc[0], 0.125f, mv[0]);
    float s1 = (mv[1] < 0.f) ? NEGH : fmaf(acc[1], 0.125f, mv[1]);
    float s2 = (mv[2] < 0.f) ? NEGH : fmaf(acc[2], 0.125f, mv[2]);
    float s3 = (mv[3] < 0.f) ? NEGH : fmaf(acc[3], 0.125f, mv[3]);
    m = fmaxf(m, fmaxf(fmaxf(s0, s1), fmaxf(s2, s3)));
    ph[2 * t]     = __builtin_amdgcn_cvt_pkrtz(s0, s1);
    ph[2 * t + 1] = __builtin_amdgcn_cvt_pkrtz(s2, s3);
  }
  // row max across the 4 g-groups holding the same q-row
  m = fmaxf(m, __shfl_xor(m, 16));
  m = fmaxf(m, __shfl_xor(m, 32));

  // ---- Phase A2: e = exp(s - m), sum, repack e over s ----
  float lw = 0.f;
#pragma unroll
  for (int t = 0; t < 32; ++t) {
    f16x2 h0 = ph[2 * t], h1 = ph[2 * t + 1];
    float e0 = __expf((float)h0[0] - m);
    float e1 = __expf((float)h0[1] - m);
    float e2 = __expf((float)h1[0] - m);
    float e3 = __expf((float)h1[1] - m);
    lw += (e0 + e1) + (e2 + e3);
    ph[2 * t]     = __builtin_amdgcn_cvt_pkrtz(e0, e1);
    ph[2 * t + 1] = __builtin_amdgcn_cvt_pkrtz(e2, e3);
  }
  lw += __shfl_xor(lw, 16);
  lw += __shfl_xor(lw, 32);

  if (lane < 16) { stat_m[w][lane] = m; stat_l[w][lane] = lw; }
  __syncthreads();

  float mg = -3.0e38f;
#pragma unroll
  for (int ww = 0; ww < 4; ++ww) mg = fmaxf(mg, stat_m[ww][l15]);
  float lg = 0.f;
#pragma unroll
  for (int ww = 0; ww < 4; ++ww) lg += stat_l[ww][l15] * __expf(stat_m[ww][l15] - mg);
  const float scale = __expf(m - mg) / lg;
  const __fp16 hs = (__fp16)scale;
  const f16x2 sc2 = {hs, hs};

  // ---- Phase B: attn stores (f32x4) + PV via 16x16x16 f16 MFMA ----
  f32x4 oacc[4];
#pragma unroll
  for (int db = 0; db < 4; ++db) oacc[db] = (f32x4){0.f, 0.f, 0.f, 0.f};

  float* attn_base = attn + ((size_t)(b * SEQ) + q0 + l15) * (size_t)SEQ + wk0 + g4;
  const __fp16* vbase = vth + ((size_t)(b * HD + l15)) * SEQ + wk0 + g4;

  f16x4 vbuf[4][4];  // 4-deep V pipeline (L2-resident)
#pragma unroll
  for (int i = 0; i < 4; ++i)
#pragma unroll
    for (int db = 0; db < 4; ++db)
      vbuf[i][db] = *(const f16x4*)(vbase + (size_t)db * (16 * SEQ) + i * 16);

#pragma unroll
  for (int t = 0; t < 32; ++t) {
    f16x2 e01 = ph[2 * t] * sc2;
    f16x2 e23 = ph[2 * t + 1] * sc2;
    f32x4 st;
    st[0] = (float)e01[0]; st[1] = (float)e01[1];
    st[2] = (float)e23[0]; st[3] = (float)e23[1];
    *(f32x4*)(attn_base + t * 16) = st;
    f16x4 pf;  // B-fragment: col=l15 -> q, k=g*4+j -> the lane's own 4 e's
    pf[0] = e01[0]; pf[1] = e01[1]; pf[2] = e23[0]; pf[3] = e23[1];
    oacc[0] = __builtin_amdgcn_mfma_f32_16x16x16f16(vbuf[t & 3][0], pf, oacc[0], 0, 0, 0);
    oacc[1] = __builtin_amdgcn_mfma_f32_16x16x16f16(vbuf[t & 3][1], pf, oacc[1], 0, 0, 0);
    oacc[2] = __builtin_amdgcn_mfma_f32_16x16x16f16(vbuf[t & 3][2], pf, oacc[2], 0, 0, 0);
    oacc[3] = __builtin_amdgcn_mfma_f32_16x16x16f16(vbuf[t & 3][3], pf, oacc[3], 0, 0, 0);
    if (t + 4 < 32) {
#pragma unroll
      for (int db = 0; db < 4; ++db)
        vbuf[t & 3][db] = *(const f16x4*)(vbase + (size_t)db * (16 * SEQ) + (t + 4) * 16);
    }
  }

  // ---- cross-wave partial-O reduction ----
  // oacc[db][r] = O^T[d = db*16 + g*4 + r][q = l15] (partial over wave's k)
#pragma unroll
  for (int db = 0; db < 4; ++db)
#pragma unroll
    for (int r = 0; r < 4; ++r)
      s_red[(size_t)w * 1088 + (db * 16 + g4 + r) * 17 + l15] = oacc[db][r];
  __syncthreads();

#pragma unroll
  for (int ii = 0; ii < 4; ++ii) {
    const int i = tid + ii * 256;     // i in [0,1024): q = i>>6, d = i&63
    const int q = i >> 6;
    const int d = i & 63;
    const int o = d * 17 + q;
    float s = s_red[o] + s_red[1088 + o] + s_red[2 * 1088 + o] + s_red[3 * 1088 + o];
    out[((size_t)(b * SEQ + q0 + q)) * HD + d] = s;
  }
}

extern "C" void kernel_launch(void* const* d_in, const int* in_sizes, int n_in,
                              void* d_out, int out_size, void* d_ws, size_t ws_size,
                              hipStream_t stream) {
  const float* q    = (const float*)d_in[0];
  const float* k    = (const float*)d_in[1];
  const float* v    = (const float*)d_in[2];
  const float* mask = (const float*)d_in[3];

  float* out  = (float*)d_out;
  float* attn = out + (size_t)BATCH * SEQ * HD;  // tuple: (output, attn)

  const size_t nqk = (size_t)BATCH * SEQ * HD;
  __fp16* qh = (__fp16*)d_ws;
  __fp16* kh = qh + nqk;
  __fp16* vt = kh + nqk;

  const int n4 = (int)(nqk / 4);
  cvt_f16_kernel<<<dim3((n4 + 255) / 256), dim3(256), 0, stream>>>(q, qh, n4);
  cvt_f16_kernel<<<dim3((n4 + 255) / 256), dim3(256), 0, stream>>>(k, kh, n4);
  vtrans_kernel<<<dim3(BATCH * (SEQ / 64)), dim3(256), 0, stream>>>(v, vt);
  attn_kernel<<<dim3(BATCH * (SEQ / 16)), dim3(256), 0, stream>>>(qh, kh, vt, mask, out, attn);
}

// Round 7
// 893.471 us; speedup vs baseline: 1.1773x; 1.1722x over previous
//
#include <hip/hip_runtime.h>
#include <stdint.h>
#include <stddef.h>

// ScaledDotProductAttention: B=64, Lq=Lk=2048, D=64, fp32 in/out.
// out tuple = (output [64][2048][64], attn [64][2048][2048]) concat in d_out.
// R7: COALESCED global I/O. Mask reads and attn writes go through a
// double-buffered LDS chunk (16 rows x 256 cols) so every global access is a
// 1KB contiguous wave-level run (f32x4 per lane from ONE row), instead of 16
// scattered 64B segments. MFMA fragment consume/produce hits LDS (cheap).
// Compute structure = R5 (swapped mfma(K,Q), lane owns q=l15 k=g*4..+3,
// packed-fp16 logits in registers, PV via 16x16x16 f16 MFMA).

typedef __attribute__((ext_vector_type(4))) float f32x4;
typedef __fp16 f16x2 __attribute__((ext_vector_type(2)));
typedef __fp16 f16x4 __attribute__((ext_vector_type(4)));
typedef __fp16 f16x8 __attribute__((ext_vector_type(8)));

static constexpr int BATCH  = 64;
static constexpr int SEQ    = 2048;  // lq == lk
static constexpr int HD     = 64;    // head dim
static constexpr int CHUNK  = 256;   // k-cols per round
static constexpr int ROUNDS = 8;     // 2048 / 256
static constexpr int LDSROW = 260;   // 256 + 4-float pad (bank rotate)
static constexpr float NEGH = -60000.0f;  // "-inf" that survives fp16

// ---------------- pre-pass: fp32 -> fp16 flat convert ----------------
__global__ void cvt_f16_kernel(const float* __restrict__ in,
                               __fp16* __restrict__ out, int n4) {
  int i = blockIdx.x * blockDim.x + threadIdx.x;
  if (i >= n4) return;
  f32x4 v = *(const f32x4*)(in + (size_t)i * 4);
  f16x4 o;
  o[0] = (__fp16)v[0]; o[1] = (__fp16)v[1];
  o[2] = (__fp16)v[2]; o[3] = (__fp16)v[3];
  *(f16x4*)(out + (size_t)i * 4) = o;
}

// ---------------- pre-pass: V [b][k][d] fp32 -> VT fp16 [b][d][k] ----------
__global__ void vtrans_kernel(const float* __restrict__ v,
                              __fp16* __restrict__ vt) {
  __shared__ float tile[64][65];
  const int b  = blockIdx.x >> 5;
  const int k0 = (blockIdx.x & 31) << 6;
  const int t  = threadIdx.x;
  const int kk = t >> 4;
  const int d4 = (t & 15) << 2;
#pragma unroll
  for (int i = 0; i < 4; ++i) {
    f32x4 val = *(const f32x4*)(v + ((size_t)(b * SEQ + k0 + kk + 16 * i)) * HD + d4);
    tile[kk + 16 * i][d4 + 0] = val[0];
    tile[kk + 16 * i][d4 + 1] = val[1];
    tile[kk + 16 * i][d4 + 2] = val[2];
    tile[kk + 16 * i][d4 + 3] = val[3];
  }
  __syncthreads();
  const int d  = t >> 2;
  const int ks = (t & 3) << 4;
  f16x8 o0, o1;
#pragma unroll
  for (int j = 0; j < 8; ++j) o0[j] = (__fp16)tile[ks + j][d];
#pragma unroll
  for (int j = 0; j < 8; ++j) o1[j] = (__fp16)tile[ks + 8 + j][d];
  __fp16* dst = vt + ((size_t)(b * HD + d)) * SEQ + k0 + ks;
  *(f16x8*)(dst)     = o0;
  *(f16x8*)(dst + 8) = o1;
}

// ---------------- main fused attention ----------------
// grid: 64 batches x 128 q-tiles; block 256 (4 waves).
// Compute ownership: wave w owns k-cols {r*256 + w*64 .. +64} per round r.
// I/O ownership:     wave w owns q-rows {4w..4w+3}, full-width coalesced.
__global__ __launch_bounds__(256, 2) void attn_kernel(
    const __fp16* __restrict__ qh,
    const __fp16* __restrict__ kh,
    const __fp16* __restrict__ vth,
    const float* __restrict__ mask,
    float* __restrict__ out,
    float* __restrict__ attn) {
  __shared__ float chunkbuf[2][16][LDSROW];  // 33.3 KB mask/attn bounce
  __shared__ float s_red[4][64 * 17];        // 17.4 KB O partials
  __shared__ float stat_m[4][16];
  __shared__ float stat_l[4][16];

  const int tid  = threadIdx.x;
  const int w    = tid >> 6;
  const int lane = tid & 63;
  const int l15  = lane & 15;
  const int g    = lane >> 4;   // 16-lane group 0..3
  const int g4   = g << 2;
  const int g8   = g << 3;

  const int b    = blockIdx.x >> 7;
  const int q0   = (blockIdx.x & 127) << 4;
  const int wk64 = w << 6;
  const int w4   = w << 2;

  // Q = B operand (col=l15 -> q-row, k=g*8+j -> head-dim)
  const __fp16* qptr = qh + ((size_t)(b * SEQ + q0 + l15)) * HD;
  const f16x8 qb0 = *(const f16x8*)(qptr + g8);
  const f16x8 qb1 = *(const f16x8*)(qptr + 32 + g8);

  // coalesced I/O base: wave w handles q-rows q0+4w+i, 16B per lane
  const float* mrow_base = mask + ((size_t)(b * SEQ) + q0 + w4) * (size_t)SEQ + lane * 4;
  float* arow_base = attn + ((size_t)(b * SEQ) + q0 + w4) * (size_t)SEQ + lane * 4;

  // ---- Phase A prologue: stage mask chunk 0 (coalesced) ----
  {
#pragma unroll
    for (int i = 0; i < 4; ++i) {
      f32x4 mv = __builtin_nontemporal_load((const f32x4*)(mrow_base + (size_t)i * SEQ));
      *(f32x4*)&chunkbuf[0][w4 + i][lane * 4] = mv;
    }
  }
  __syncthreads();

  // ---- Phase A: S^T = mfma(K,Q)/8 + mask -> packed fp16 regs + running max
  f16x2 ph[64];   // 8 rounds x 4 subtiles x 2 pairs
  float m = -3.0e38f;

#pragma unroll
  for (int r = 0; r < ROUNDS; ++r) {
    // issue next chunk's coalesced mask loads early (T14: issue-early)
    f32x4 mld[4];
    if (r + 1 < ROUNDS) {
#pragma unroll
      for (int i = 0; i < 4; ++i)
        mld[i] = __builtin_nontemporal_load(
            (const f32x4*)(mrow_base + (size_t)i * SEQ + (r + 1) * CHUNK));
    }
    // compute 4 MFMA subtiles from LDS chunk r
#pragma unroll
    for (int t = 0; t < 4; ++t) {
      const __fp16* kp =
          kh + ((size_t)(b * SEQ) + r * CHUNK + wk64 + t * 16 + l15) * HD;
      const f16x8 ka0 = *(const f16x8*)(kp + g8);
      const f16x8 ka1 = *(const f16x8*)(kp + 32 + g8);
      f32x4 acc = {0.f, 0.f, 0.f, 0.f};
      acc = __builtin_amdgcn_mfma_f32_16x16x32_f16(ka0, qb0, acc, 0, 0, 0);
      acc = __builtin_amdgcn_mfma_f32_16x16x32_f16(ka1, qb1, acc, 0, 0, 0);
      const f32x4 mv = *(const f32x4*)&chunkbuf[r & 1][l15][wk64 + t * 16 + g4];
      float s0 = (mv[0] < 0.f) ? NEGH : fmaf(acc[0], 0.125f, mv[0]);
      float s1 = (mv[1] < 0.f) ? NEGH : fmaf(acc[1], 0.125f, mv[1]);
      float s2 = (mv[2] < 0.f) ? NEGH : fmaf(acc[2], 0.125f, mv[2]);
      float s3 = (mv[3] < 0.f) ? NEGH : fmaf(acc[3], 0.125f, mv[3]);
      m = fmaxf(m, fmaxf(fmaxf(s0, s1), fmaxf(s2, s3)));
      ph[r * 8 + 2 * t]     = __builtin_amdgcn_cvt_pkrtz(s0, s1);
      ph[r * 8 + 2 * t + 1] = __builtin_amdgcn_cvt_pkrtz(s2, s3);
    }
    // write next chunk to the other buffer, one barrier per round
    if (r + 1 < ROUNDS) {
#pragma unroll
      for (int i = 0; i < 4; ++i)
        *(f32x4*)&chunkbuf[(r + 1) & 1][w4 + i][lane * 4] = mld[i];
      __syncthreads();
    }
  }

  // row max across the 4 g-groups holding the same q-row
  m = fmaxf(m, __shfl_xor(m, 16));
  m = fmaxf(m, __shfl_xor(m, 32));

  // ---- Phase A2: e = exp(s - m), sum, repack e over s ----
  float lw = 0.f;
#pragma unroll
  for (int t = 0; t < 32; ++t) {
    f16x2 h0 = ph[2 * t], h1 = ph[2 * t + 1];
    float e0 = __expf((float)h0[0] - m);
    float e1 = __expf((float)h0[1] - m);
    float e2 = __expf((float)h1[0] - m);
    float e3 = __expf((float)h1[1] - m);
    lw += (e0 + e1) + (e2 + e3);
    ph[2 * t]     = __builtin_amdgcn_cvt_pkrtz(e0, e1);
    ph[2 * t + 1] = __builtin_amdgcn_cvt_pkrtz(e2, e3);
  }
  lw += __shfl_xor(lw, 16);
  lw += __shfl_xor(lw, 32);

  if (lane < 16) { stat_m[w][lane] = m; stat_l[w][lane] = lw; }
  __syncthreads();

  float mg = -3.0e38f;
#pragma unroll
  for (int ww = 0; ww < 4; ++ww) mg = fmaxf(mg, stat_m[ww][l15]);
  float lg = 0.f;
#pragma unroll
  for (int ww = 0; ww < 4; ++ww) lg += stat_l[ww][l15] * __expf(stat_m[ww][l15] - mg);
  const float scale = __expf(m - mg) / lg;
  const __fp16 hs = (__fp16)scale;
  const f16x2 sc2 = {hs, hs};

  // ---- Phase B: e-frags -> LDS -> coalesced attn stores; PV MFMA ----
  f32x4 oacc[4];
#pragma unroll
  for (int db = 0; db < 4; ++db) oacc[db] = (f32x4){0.f, 0.f, 0.f, 0.f};

  const __fp16* vbase = vth + ((size_t)(b * HD + l15)) * SEQ;

#pragma unroll
  for (int r = 0; r < ROUNDS; ++r) {
#pragma unroll
    for (int t = 0; t < 4; ++t) {
      const int col = r * CHUNK + wk64 + t * 16 + g4;
      const f16x4 vf0 = *(const f16x4*)(vbase + (size_t)(0 * 16) * SEQ + col);
      const f16x4 vf1 = *(const f16x4*)(vbase + (size_t)(1 * 16) * SEQ + col);
      const f16x4 vf2 = *(const f16x4*)(vbase + (size_t)(2 * 16) * SEQ + col);
      const f16x4 vf3 = *(const f16x4*)(vbase + (size_t)(3 * 16) * SEQ + col);
      f16x2 e01 = ph[r * 8 + 2 * t] * sc2;
      f16x2 e23 = ph[r * 8 + 2 * t + 1] * sc2;
      f32x4 st;
      st[0] = (float)e01[0]; st[1] = (float)e01[1];
      st[2] = (float)e23[0]; st[3] = (float)e23[1];
      *(f32x4*)&chunkbuf[r & 1][l15][wk64 + t * 16 + g4] = st;
      f16x4 pf;  // B-fragment: col=l15 -> q, k=g*4+j -> the lane's own 4 e's
      pf[0] = e01[0]; pf[1] = e01[1]; pf[2] = e23[0]; pf[3] = e23[1];
      oacc[0] = __builtin_amdgcn_mfma_f32_16x16x16f16(vf0, pf, oacc[0], 0, 0, 0);
      oacc[1] = __builtin_amdgcn_mfma_f32_16x16x16f16(vf1, pf, oacc[1], 0, 0, 0);
      oacc[2] = __builtin_amdgcn_mfma_f32_16x16x16f16(vf2, pf, oacc[2], 0, 0, 0);
      oacc[3] = __builtin_amdgcn_mfma_f32_16x16x16f16(vf3, pf, oacc[3], 0, 0, 0);
    }
    __syncthreads();
    // coalesced attn store: wave w stores its 4 rows, 1KB runs
#pragma unroll
    for (int i = 0; i < 4; ++i) {
      const f32x4 vsto = *(const f32x4*)&chunkbuf[r & 1][w4 + i][lane * 4];
      __builtin_nontemporal_store(vsto,
          (f32x4*)(arow_base + (size_t)i * SEQ + r * CHUNK));
    }
  }

  // ---- cross-wave partial-O reduction ----
  // oacc[db][r] = O^T[d = db*16 + g*4 + r][q = l15] (partial over wave's k)
#pragma unroll
  for (int db = 0; db < 4; ++db)
#pragma unroll
    for (int rr = 0; rr < 4; ++rr)
      s_red[w][(db * 16 + g4 + rr) * 17 + l15] = oacc[db][rr];
  __syncthreads();

#pragma unroll
  for (int ii = 0; ii < 4; ++ii) {
    const int i = tid + ii * 256;     // i in [0,1024): q = i>>6, d = i&63
    const int q = i >> 6;
    const int d = i & 63;
    const int o = d * 17 + q;
    float s = s_red[0][o] + s_red[1][o] + s_red[2][o] + s_red[3][o];
    out[((size_t)(b * SEQ + q0 + q)) * HD + d] = s;
  }
}

extern "C" void kernel_launch(void* const* d_in, const int* in_sizes, int n_in,
                              void* d_out, int out_size, void* d_ws, size_t ws_size,
                              hipStream_t stream) {
  const float* q    = (const float*)d_in[0];
  const float* k    = (const float*)d_in[1];
  const float* v    = (const float*)d_in[2];
  const float* mask = (const float*)d_in[3];

  float* out  = (float*)d_out;
  float* attn = out + (size_t)BATCH * SEQ * HD;  // tuple: (output, attn)

  const size_t nqk = (size_t)BATCH * SEQ * HD;
  __fp16* qh = (__fp16*)d_ws;
  __fp16* kh = qh + nqk;
  __fp16* vt = kh + nqk;

  const int n4 = (int)(nqk / 4);
  cvt_f16_kernel<<<dim3((n4 + 255) / 256), dim3(256), 0, stream>>>(q, qh, n4);
  cvt_f16_kernel<<<dim3((n4 + 255) / 256), dim3(256), 0, stream>>>(k, kh, n4);
  vtrans_kernel<<<dim3(BATCH * (SEQ / 64)), dim3(256), 0, stream>>>(v, vt);
  attn_kernel<<<dim3(BATCH * (SEQ / 16)), dim3(256), 0, stream>>>(qh, kh, vt, mask, out, attn);
}